// Round 4
// baseline (168.342 us; speedup 1.0000x reference)
//
#include <hip/hip_runtime.h>

// Problem constants (B=1)
#define T_LEN 2048
#define C_DIM 1024
#define H_NUM 16
#define D_DIM 64
#define QKV_N (3 * H_NUM * D_DIM)   // 3072
#define L_CHK 64
#define NC (T_LEN / L_CHK)          // 32

typedef _Float16 h8 __attribute__((ext_vector_type(8)));
typedef _Float16 h4 __attribute__((ext_vector_type(4)));
typedef float f32x4 __attribute__((ext_vector_type(4)));

// ---------------------------------------------------------------------------
// Fused fp32 -> fp16 split, scale 64. x & w_attn get hi+lo; w_proj hi only.
// ---------------------------------------------------------------------------
__global__ __launch_bounds__(256) void split3_f16(
    const float* __restrict__ x, _Float16* __restrict__ xh,
    _Float16* __restrict__ xl, const float* __restrict__ wa,
    _Float16* __restrict__ wah, _Float16* __restrict__ wal,
    const float* __restrict__ wp, _Float16* __restrict__ wph) {
  int i = (blockIdx.x * 256 + threadIdx.x) * 8;
  const float* src;
  _Float16 *dh, *dl = nullptr;
  int base;
  if (i < 2097152) {
    src = x; dh = xh; dl = xl; base = i;
  } else if (i < 2097152 + 3145728) {
    src = wa; dh = wah; dl = wal; base = i - 2097152;
  } else {
    src = wp; dh = wph; base = i - 5242880;
  }
  float4 a = *(const float4*)(src + base);
  float4 b = *(const float4*)(src + base + 4);
  float v[8] = {a.x, a.y, a.z, a.w, b.x, b.y, b.z, b.w};
  h8 hv, lv;
#pragma unroll
  for (int j = 0; j < 8; ++j) {
    float s = v[j] * 64.f;
    _Float16 h = (_Float16)s;
    hv[j] = h;
    lv[j] = (_Float16)(s - (float)h);
  }
  *(h8*)(dh + base) = hv;
  if (dl) *(h8*)(dl + base) = lv;
}

// fp32 octet -> fp16 hi/lo fragments
__device__ __forceinline__ void split8(float4 a, float4 b, h8& hi, h8& lo) {
  float v[8] = {a.x, a.y, a.z, a.w, b.x, b.y, b.z, b.w};
#pragma unroll
  for (int m = 0; m < 8; ++m) {
    _Float16 hh = (_Float16)v[m];
    hi[m] = hh;
    lo[m] = (_Float16)(v[m] - (float)hh);
  }
}

// ---------------------------------------------------------------------------
// fp16 NT MFMA GEMM, BK=64, XOR-swizzled LDS (16B-block granularity).
// SPLIT3: acc += Ah*Bh + Ah*Bl + Al*Bh (fp32-grade). !SPLIT3: 1 MFMA.
// Tile BM x BN, 256 thr = 2x2 waves, each wave owns (BM/2)x(BN/2):
//   BM=BN=128 (QKV): wave=64x64, 4x4 frags -> MFMA:ds_read = 3:1 (m97 geom)
//   BM=BN=64 (proj): wave=32x32, 2x2 frags
// ROPE epilogue (128x128): each 64-col wave-half == one q/k/v block of one
// head. Deduped cos/sin [128][32] staged in (dead) A-region; per-wave 16 KB
// fp32 bounce regions (XOR d^t swizzle) for transposed k/v stores.
// ---------------------------------------------------------------------------
template <int BM, int BN, bool ROPE, bool SPLIT3>
__global__ __launch_bounds__(256, 2) void gemm_nt_f16(
    const _Float16* __restrict__ Ah, const _Float16* __restrict__ Al,
    const _Float16* __restrict__ Bh, const _Float16* __restrict__ Bl,
    float* __restrict__ C, const float* __restrict__ cosb,
    const float* __restrict__ sinb, _Float16* __restrict__ qh_,
    _Float16* __restrict__ ql_, _Float16* __restrict__ kh_,
    _Float16* __restrict__ kl_, _Float16* __restrict__ kTh_,
    _Float16* __restrict__ kTl_, _Float16* __restrict__ vTh_,
    _Float16* __restrict__ vTl_, int M, int N, int K, float outscale) {
  constexpr int MI = BM / 32;  // M-frags per wave
  constexpr int NJ = BN / 32;  // N-frags per wave
  constexpr int NARR = SPLIT3 ? 2 : 1;
  constexpr int GEMM_BYTES = (BM * 64 * 2 + BN * 64 * 2) * NARR;
  constexpr int ROPE_BYTES = ROPE ? 65536 : 0;
  constexpr int SMEM_BYTES = GEMM_BYTES > ROPE_BYTES ? GEMM_BYTES : ROPE_BYTES;
  __shared__ __align__(16) char smem[SMEM_BYTES];
  _Float16* sAh = (_Float16*)smem;
  _Float16* sAl = sAh + BM * 64;                       // SPLIT3 only
  _Float16* sBh = sAh + BM * 64 * NARR;
  _Float16* sBl = sBh + BN * 64;                       // SPLIT3 only
  const int tid = threadIdx.x;
  const int wave = tid >> 6;
  const int lane = tid & 63;
  const int bm = blockIdx.y * BM;
  const int bn = blockIdx.x * BN;
  const int wm = wave >> 1;          // 0..1 -> BM/2-row half
  const int wn = wave & 1;           // 0..1 -> BN/2-col half
  const int srow = lane >> 3;        // 0..7 staging row within chunk
  const int sblk = ((lane & 7) ^ srow) * 8;  // swizzled col block (halves)
  const int quad = lane >> 4;        // 0..3
  const int lrow = lane & 15;

  f32x4 acc[MI][NJ];
#pragma unroll
  for (int i = 0; i < MI; ++i)
#pragma unroll
    for (int j = 0; j < NJ; ++j) acc[i][j] = (f32x4){0.f, 0.f, 0.f, 0.f};

  for (int k0 = 0; k0 < K; k0 += 64) {
#pragma unroll
    for (int it = 0; it < MI; ++it) {
      const int ch = wave + it * 4;  // 0..BM/8-1
      const int row = ch * 8 + srow;
      const _Float16* ga = Ah + (size_t)(bm + row) * K + k0 + sblk;
      __builtin_amdgcn_global_load_lds(
          (const __attribute__((address_space(1))) void*)ga,
          (__attribute__((address_space(3))) void*)(sAh + ch * 512), 16, 0, 0);
      if constexpr (SPLIT3) {
        const _Float16* gb = Al + (size_t)(bm + row) * K + k0 + sblk;
        __builtin_amdgcn_global_load_lds(
            (const __attribute__((address_space(1))) void*)gb,
            (__attribute__((address_space(3))) void*)(sAl + ch * 512), 16, 0,
            0);
      }
    }
#pragma unroll
    for (int it = 0; it < NJ; ++it) {
      const int ch = wave + it * 4;  // 0..BN/8-1
      const int row = ch * 8 + srow;
      const _Float16* ga = Bh + (size_t)(bn + row) * K + k0 + sblk;
      __builtin_amdgcn_global_load_lds(
          (const __attribute__((address_space(1))) void*)ga,
          (__attribute__((address_space(3))) void*)(sBh + ch * 512), 16, 0, 0);
      if constexpr (SPLIT3) {
        const _Float16* gb = Bl + (size_t)(bn + row) * K + k0 + sblk;
        __builtin_amdgcn_global_load_lds(
            (const __attribute__((address_space(1))) void*)gb,
            (__attribute__((address_space(3))) void*)(sBl + ch * 512), 16, 0,
            0);
      }
    }
    __syncthreads();
#pragma unroll
    for (int kk = 0; kk < 2; ++kk) {
      h8 ah[MI], al[MI], bh[NJ], bl[NJ];
#pragma unroll
      for (int i = 0; i < MI; ++i) {
        const int row = wm * (BM / 2) + i * 16 + lrow;
        const int ra = row * 64 + (((kk * 4 + quad) ^ (row & 7)) * 8);
        ah[i] = *(const h8*)&sAh[ra];
        if constexpr (SPLIT3) al[i] = *(const h8*)&sAl[ra];
      }
#pragma unroll
      for (int j = 0; j < NJ; ++j) {
        const int row = wn * (BN / 2) + j * 16 + lrow;
        const int rb = row * 64 + (((kk * 4 + quad) ^ (row & 7)) * 8);
        bh[j] = *(const h8*)&sBh[rb];
        if constexpr (SPLIT3) bl[j] = *(const h8*)&sBl[rb];
      }
#pragma unroll
      for (int i = 0; i < MI; ++i)
#pragma unroll
        for (int j = 0; j < NJ; ++j) {
          acc[i][j] = __builtin_amdgcn_mfma_f32_16x16x32_f16(
              ah[i], bh[j], acc[i][j], 0, 0, 0);
          if constexpr (SPLIT3) {
            acc[i][j] = __builtin_amdgcn_mfma_f32_16x16x32_f16(
                ah[i], bl[j], acc[i][j], 0, 0, 0);
            acc[i][j] = __builtin_amdgcn_mfma_f32_16x16x32_f16(
                al[i], bh[j], acc[i][j], 0, 0, 0);
          }
        }
    }
    __syncthreads();
  }
  // epilogue: C/D layout col=lane&15, row=quad*4+reg
  if constexpr (!ROPE) {
#pragma unroll
    for (int i = 0; i < MI; ++i) {
      const int rbase = bm + wm * (BM / 2) + i * 16 + quad * 4;
#pragma unroll
      for (int j = 0; j < NJ; ++j) {
        const int col = bn + wn * (BN / 2) + j * 16 + lrow;
#pragma unroll
        for (int r = 0; r < 4; ++r)
          C[(size_t)(rbase + r) * N + col] = acc[i][j][r] * outscale;
      }
    }
  } else {
    // BM == BN == 128 here.
    float* cs = (float*)smem;        // [128][32] deduped cos (16 KB)
    float* sn = cs + 4096;           // [128][32] deduped sin (16 KB)
    {
      const int t = tid >> 1, d0 = (tid & 1) * 16;
      const float* gc = &cosb[(size_t)(bm + t) * D_DIM + d0];
      const float* gs = &sinb[(size_t)(bm + t) * D_DIM + d0];
      *(float4*)&cs[t * 32 + d0] = *(const float4*)gc;
      *(float4*)&cs[t * 32 + d0 + 4] = *(const float4*)(gc + 4);
      *(float4*)&cs[t * 32 + d0 + 8] = *(const float4*)(gc + 8);
      *(float4*)&cs[t * 32 + d0 + 12] = *(const float4*)(gc + 12);
      *(float4*)&sn[t * 32 + d0] = *(const float4*)gs;
      *(float4*)&sn[t * 32 + d0 + 4] = *(const float4*)(gs + 4);
      *(float4*)&sn[t * 32 + d0 + 8] = *(const float4*)(gs + 8);
      *(float4*)&sn[t * 32 + d0 + 12] = *(const float4*)(gs + 12);
    }
    __syncthreads();
    const int colbase = bn + wn * 64;
    const int type = (colbase >> 6) % 3;    // 0=q, 1=k, 2=v
    const int head = colbase / 192;
    const size_t hb = (size_t)head * T_LEN * D_DIM;
    // final fp32 values (rope applied for q/k), fv[i][reg][j]
    float fv[4][4][4];
#pragma unroll
    for (int i = 0; i < 4; ++i)
#pragma unroll
      for (int r = 0; r < 4; ++r) {
        const int tloc = wm * 64 + i * 16 + quad * 4 + r;
#pragma unroll
        for (int j = 0; j < 4; ++j) {
          const int d32 = (j & 1) * 16 + lrow;   // d mod 32
          float val = acc[i][j][r] * outscale;
          if (type < 2) {
            float rotv =
                ((j < 2) ? -acc[i][j + 2][r] : acc[i][j - 2][r]) * outscale;
            val = val * cs[tloc * 32 + d32] + rotv * sn[tloc * 32 + d32];
          }
          fv[i][r][j] = val;
        }
      }
    // direct (t,d) fp16 hi/lo stores for q and k
    if (type < 2) {
      _Float16* dh = (type == 0 ? qh_ : kh_) + hb;
      _Float16* dl = (type == 0 ? ql_ : kl_) + hb;
#pragma unroll
      for (int i = 0; i < 4; ++i)
#pragma unroll
        for (int r = 0; r < 4; ++r) {
          const size_t trow =
              (size_t)(bm + wm * 64 + i * 16 + quad * 4 + r) * D_DIM;
#pragma unroll
          for (int j = 0; j < 4; ++j) {
            const int d = j * 16 + lrow;
            float f = fv[i][r][j];
            _Float16 hh = (_Float16)f;
            dh[trow + d] = hh;
            dl[trow + d] = (_Float16)(f - (float)hh);
          }
        }
    }
    // transposed (d,t) stores for k and v via per-wave 16 KB bounce regions
    // (cos/sin tables are dead now; full 64 KB reusable).
    const bool doT = (type >= 1);
    _Float16* th = (type == 1 ? kTh_ : vTh_) + hb;
    _Float16* tl = (type == 1 ? kTl_ : vTl_) + hb;
    float* myb = (float*)smem + wave * 4096;
    __syncthreads();
    if (doT) {
#pragma unroll
      for (int i = 0; i < 4; ++i)
#pragma unroll
        for (int r = 0; r < 4; ++r) {
          const int tl64 = i * 16 + quad * 4 + r;   // wave-local t
#pragma unroll
          for (int j = 0; j < 4; ++j) {
            const int d = j * 16 + lrow;
            myb[tl64 * 64 + (d ^ tl64)] = fv[i][r][j];
          }
        }
    }
    __syncthreads();
    if (doT) {
      const int e = lane;              // output row (dim)
      const size_t obase = (size_t)e * T_LEN + bm + wm * 64;
#pragma unroll
      for (int s8 = 0; s8 < 8; ++s8) {
        h8 hv, lv;
#pragma unroll
        for (int s = 0; s < 8; ++s) {
          const int t = s8 * 8 + s;
          float f = myb[t * 64 + (e ^ t)];
          _Float16 hh = (_Float16)f;
          hv[s] = hh;
          lv[s] = (_Float16)(f - (float)hh);
        }
        *(h8*)&th[obase + s8 * 8] = hv;
        *(h8*)&tl[obase + s8 * 8] = lv;
      }
    }
  }
}

// ---------------------------------------------------------------------------
// Per-(head,chunk) KV^T via MFMA: kvT[e][d] = sum_t v[t][e]*k[t][d]
// fragments loaded global-direct (no LDS, no barriers). split3 hi/lo.
// Also emits kschunk/vschunk vectors (per-chunk row sums of kT/vT).
// ---------------------------------------------------------------------------
__global__ __launch_bounds__(256) void chunk_kvT(
    const _Float16* __restrict__ kTh, const _Float16* __restrict__ kTl,
    const _Float16* __restrict__ vTh, const _Float16* __restrict__ vTl,
    float* __restrict__ kvchunk, float* __restrict__ kschunk,
    float* __restrict__ vschunk) {
  const int blk = blockIdx.x;  // h*NC + c
  const int h = blk / NC, c = blk % NC;
  const int tid = threadIdx.x;
  const int wave = tid >> 6, lane = tid & 63;
  const int quad = lane >> 4, lrow = lane & 15;
  const size_t hb = (size_t)h * D_DIM * T_LEN;
  const int tb = c * L_CHK;
  // A-frags: vT rows e = wave*16+lrow, t-range = ks*32 + quad*8
  h8 avh[2], avl[2];
  {
    const _Float16* pa = vTh + hb + (size_t)(wave * 16 + lrow) * T_LEN + tb +
                         quad * 8;
    const _Float16* pal = vTl + hb + (size_t)(wave * 16 + lrow) * T_LEN + tb +
                          quad * 8;
    avh[0] = *(const h8*)pa;
    avh[1] = *(const h8*)(pa + 32);
    avl[0] = *(const h8*)pal;
    avl[1] = *(const h8*)(pal + 32);
  }
  f32x4 accv[4];
#pragma unroll
  for (int dt = 0; dt < 4; ++dt) accv[dt] = (f32x4){0.f, 0.f, 0.f, 0.f};
#pragma unroll
  for (int dt = 0; dt < 4; ++dt) {
    const _Float16* pb = kTh + hb + (size_t)(dt * 16 + lrow) * T_LEN + tb +
                         quad * 8;
    const _Float16* pbl = kTl + hb + (size_t)(dt * 16 + lrow) * T_LEN + tb +
                          quad * 8;
#pragma unroll
    for (int ks = 0; ks < 2; ++ks) {
      h8 bh = *(const h8*)(pb + ks * 32);
      h8 bl = *(const h8*)(pbl + ks * 32);
      accv[dt] = __builtin_amdgcn_mfma_f32_16x16x32_f16(avh[ks], bh, accv[dt],
                                                        0, 0, 0);
      accv[dt] = __builtin_amdgcn_mfma_f32_16x16x32_f16(avh[ks], bl, accv[dt],
                                                        0, 0, 0);
      accv[dt] = __builtin_amdgcn_mfma_f32_16x16x32_f16(avl[ks], bh, accv[dt],
                                                        0, 0, 0);
    }
  }
  // store kvT: row e = wave*16 + quad*4 + reg, col d = dt*16 + lrow
  float* ob = kvchunk + (size_t)blk * (D_DIM * D_DIM);
#pragma unroll
  for (int dt = 0; dt < 4; ++dt)
#pragma unroll
    for (int r = 0; r < 4; ++r)
      ob[(wave * 16 + quad * 4 + r) * D_DIM + dt * 16 + lrow] = accv[dt][r];
  // ksum / vsum (exact sum of hi+lo in fp32)
  if (tid < 64) {
    const _Float16* p = kTh + hb + (size_t)tid * T_LEN + tb;
    const _Float16* pl = kTl + hb + (size_t)tid * T_LEN + tb;
    float s = 0.f;
#pragma unroll
    for (int i = 0; i < 8; ++i) {
      h8 a = *(const h8*)(p + i * 8), b = *(const h8*)(pl + i * 8);
#pragma unroll
      for (int m = 0; m < 8; ++m) s += (float)a[m] + (float)b[m];
    }
    kschunk[(size_t)blk * D_DIM + tid] = s;
  } else if (tid < 128) {
    const int e = tid - 64;
    const _Float16* p = vTh + hb + (size_t)e * T_LEN + tb;
    const _Float16* pl = vTl + hb + (size_t)e * T_LEN + tb;
    float s = 0.f;
#pragma unroll
    for (int i = 0; i < 8; ++i) {
      h8 a = *(const h8*)(p + i * 8), b = *(const h8*)(pl + i * 8);
#pragma unroll
      for (int m = 0; m < 8; ++m) s += (float)a[m] + (float)b[m];
    }
    vschunk[(size_t)blk * D_DIM + e] = s;
  }
}

// ---------------------------------------------------------------------------
// Fused exclusive prefix scans over chunks: blocks 0..255 do the D*D state,
// blocks 256..259 do the ksum/vsum vectors. Fully unrolled loads.
// ---------------------------------------------------------------------------
__global__ __launch_bounds__(256) void scan_fused(
    const float* __restrict__ kvchunk, float* __restrict__ kvpref,
    const float* __restrict__ kschunk, const float* __restrict__ vschunk,
    float* __restrict__ kspref, float* __restrict__ vspref) {
  int b = blockIdx.x;
  int tid = threadIdx.x;
  if (b < 256) {
    int gid = b * 256 + tid;  // h*4096 + de
    int h = gid >> 12;
    int de = gid & 4095;
    float vals[NC];
#pragma unroll
    for (int c = 0; c < NC; ++c)
      vals[c] = kvchunk[((size_t)(h * NC + c) << 12) + de];
    float run = 0.f;
#pragma unroll
    for (int c = 0; c < NC; ++c) {
      kvpref[((size_t)(h * NC + c) << 12) + de] = run;
      run += vals[c];
    }
  } else {
    int gid = (b - 256) * 256 + tid;  // h*64 + d (total 1024)
    int h = gid >> 6, d = gid & 63;
    float kv_[NC], vv_[NC];
#pragma unroll
    for (int c = 0; c < NC; ++c) {
      size_t idx = (size_t)(h * NC + c) * 64 + d;
      kv_[c] = kschunk[idx];
      vv_[c] = vschunk[idx];
    }
    float rk = 0.f, rv = 0.f;
#pragma unroll
    for (int c = 0; c < NC; ++c) {
      size_t idx = (size_t)(h * NC + c) * 64 + d;
      kspref[idx] = rk;
      vspref[idx] = rv;
      rk += kv_[c];
      rv += vv_[c];
    }
  }
}

// ---------------------------------------------------------------------------
// MFMA attention output. One block per (h,c), 4 waves; wave w owns the
// 16-row band r in [w*16, w*16+16) x all 64 e-cols.
//   S = Q K^T (split3 MFMA, global-direct frags) -> mask/+1 in fp32 ->
//   fp16 hi/lo, staged in wave-private swizzled LDS band ->
//   rowsum via ones-fragment MFMA; out = vsp + S.V + q.KVTpref (split3);
//   den = c*64 + rowsum + q.kspref (ones-style broadcast fragment).
// No __syncthreads anywhere (all LDS is wave-private).
// ---------------------------------------------------------------------------
__global__ __launch_bounds__(256) void attn_mfma(
    const _Float16* __restrict__ qh, const _Float16* __restrict__ ql,
    const _Float16* __restrict__ kh, const _Float16* __restrict__ kl,
    const _Float16* __restrict__ vTh, const _Float16* __restrict__ vTl,
    const float* __restrict__ kvpref, const float* __restrict__ kspref,
    const float* __restrict__ vspref, _Float16* __restrict__ yh) {
  __shared__ __align__(16) _Float16 sS[2][4][16 * 64];  // [plane][wave][r*64+j]
  const int blk = blockIdx.x;  // h*NC + c
  const int h = blk / NC, c = blk % NC;
  const int tid = threadIdx.x;
  const int wave = tid >> 6, lane = tid & 63;
  const int quad = lane >> 4, lrow = lane & 15;
  const size_t hb = (size_t)h * T_LEN * D_DIM;   // (t,d) arrays
  const size_t hbT = (size_t)h * D_DIM * T_LEN;  // (e,t) arrays
  const int t0 = c * L_CHK;
  const f32x4 z4 = {0.f, 0.f, 0.f, 0.f};
  // Q A-frags: rows t0 + wave*16 + lrow, d-range ks*32 + quad*8
  h8 aqh[2], aql[2];
  {
    const _Float16* pq =
        qh + hb + (size_t)(t0 + wave * 16 + lrow) * D_DIM + quad * 8;
    const _Float16* pql =
        ql + hb + (size_t)(t0 + wave * 16 + lrow) * D_DIM + quad * 8;
    aqh[0] = *(const h8*)pq;
    aqh[1] = *(const h8*)(pq + 32);
    aql[0] = *(const h8*)pql;
    aql[1] = *(const h8*)(pql + 32);
  }
  // Phase 1: S = Q K^T (within-chunk), 4 col-tiles
  f32x4 sacc[4];
#pragma unroll
  for (int jt = 0; jt < 4; ++jt) sacc[jt] = z4;
#pragma unroll
  for (int jt = 0; jt < 4; ++jt) {
    const _Float16* pk =
        kh + hb + (size_t)(t0 + jt * 16 + lrow) * D_DIM + quad * 8;
    const _Float16* pkl =
        kl + hb + (size_t)(t0 + jt * 16 + lrow) * D_DIM + quad * 8;
#pragma unroll
    for (int ks = 0; ks < 2; ++ks) {
      h8 bh = *(const h8*)(pk + ks * 32);
      h8 bl = *(const h8*)(pkl + ks * 32);
      sacc[jt] = __builtin_amdgcn_mfma_f32_16x16x32_f16(aqh[ks], bh, sacc[jt],
                                                        0, 0, 0);
      sacc[jt] = __builtin_amdgcn_mfma_f32_16x16x32_f16(aqh[ks], bl, sacc[jt],
                                                        0, 0, 0);
      sacc[jt] = __builtin_amdgcn_mfma_f32_16x16x32_f16(aql[ks], bh, sacc[jt],
                                                        0, 0, 0);
    }
  }
  // mask, +1, fp16 split, stage (swizzled: 8-half blocks XOR'd by row&7)
  _Float16* shp = &sS[0][wave][0];
  _Float16* slp = &sS[1][wave][0];
#pragma unroll
  for (int jt = 0; jt < 4; ++jt)
#pragma unroll
    for (int r = 0; r < 4; ++r) {
      const int row = quad * 4 + r;          // band-local row
      const int j = jt * 16 + lrow;          // chunk-local col
      const int rglob = wave * 16 + row;
      float s = (j <= rglob) ? (sacc[jt][r] + 1.f) : 0.f;
      _Float16 hh = (_Float16)s;
      const int adr = row * 64 + ((((j >> 3) ^ (row & 7)) << 3) | (j & 7));
      shp[adr] = hh;
      slp[adr] = (_Float16)(s - (float)hh);
    }
  // S A-frags (own band, same-wave LDS dependency: compiler orders lgkmcnt)
  h8 ash[2], asl[2];
#pragma unroll
  for (int ks = 0; ks < 2; ++ks) {
    const int adr = lrow * 64 + (((ks * 4 + quad) ^ (lrow & 7)) << 3);
    ash[ks] = *(const h8*)&shp[adr];
    asl[ks] = *(const h8*)&slp[adr];
  }
  // rowsum(S) via ones-fragment (exact: Sh+Sl)
  h8 ones;
#pragma unroll
  for (int m = 0; m < 8; ++m) ones[m] = (_Float16)1.0f;
  f32x4 rs = z4;
#pragma unroll
  for (int ks = 0; ks < 2; ++ks) {
    rs = __builtin_amdgcn_mfma_f32_16x16x32_f16(ash[ks], ones, rs, 0, 0, 0);
    rs = __builtin_amdgcn_mfma_f32_16x16x32_f16(asl[ks], ones, rs, 0, 0, 0);
  }
  // out accumulation: S.V + q.KVTpref
  f32x4 oacc[4];
#pragma unroll
  for (int et = 0; et < 4; ++et) oacc[et] = z4;
#pragma unroll
  for (int et = 0; et < 4; ++et) {
    const _Float16* pv =
        vTh + hbT + (size_t)(et * 16 + lrow) * T_LEN + t0 + quad * 8;
    const _Float16* pvl =
        vTl + hbT + (size_t)(et * 16 + lrow) * T_LEN + t0 + quad * 8;
#pragma unroll
    for (int ks = 0; ks < 2; ++ks) {
      h8 bh = *(const h8*)(pv + ks * 32);
      h8 bl = *(const h8*)(pvl + ks * 32);
      oacc[et] = __builtin_amdgcn_mfma_f32_16x16x32_f16(ash[ks], bh, oacc[et],
                                                        0, 0, 0);
      oacc[et] = __builtin_amdgcn_mfma_f32_16x16x32_f16(ash[ks], bl, oacc[et],
                                                        0, 0, 0);
      oacc[et] = __builtin_amdgcn_mfma_f32_16x16x32_f16(asl[ks], bh, oacc[et],
                                                        0, 0, 0);
    }
  }
  const float* kvp = kvpref + (size_t)blk * (D_DIM * D_DIM);
#pragma unroll
  for (int et = 0; et < 4; ++et) {
#pragma unroll
    for (int ks = 0; ks < 2; ++ks) {
      const float* pb = kvp + (et * 16 + lrow) * D_DIM + ks * 32 + quad * 8;
      float4 b0 = *(const float4*)pb;
      float4 b1 = *(const float4*)(pb + 4);
      h8 bh, bl;
      split8(b0, b1, bh, bl);
      oacc[et] = __builtin_amdgcn_mfma_f32_16x16x32_f16(aqh[ks], bh, oacc[et],
                                                        0, 0, 0);
      oacc[et] = __builtin_amdgcn_mfma_f32_16x16x32_f16(aqh[ks], bl, oacc[et],
                                                        0, 0, 0);
      oacc[et] = __builtin_amdgcn_mfma_f32_16x16x32_f16(aql[ks], bh, oacc[et],
                                                        0, 0, 0);
    }
  }
  // den extra: q . kspref via broadcast fragment (all cols identical)
  const float* ksp = kspref + (size_t)blk * D_DIM;
  f32x4 kacc = z4;
#pragma unroll
  for (int ks = 0; ks < 2; ++ks) {
    const float* pb = ksp + ks * 32 + quad * 8;
    float4 b0 = *(const float4*)pb;
    float4 b1 = *(const float4*)(pb + 4);
    h8 bh, bl;
    split8(b0, b1, bh, bl);
    kacc = __builtin_amdgcn_mfma_f32_16x16x32_f16(aqh[ks], bh, kacc, 0, 0, 0);
    kacc = __builtin_amdgcn_mfma_f32_16x16x32_f16(aqh[ks], bl, kacc, 0, 0, 0);
    kacc = __builtin_amdgcn_mfma_f32_16x16x32_f16(aql[ks], bh, kacc, 0, 0, 0);
  }
  // epilogue: den = c*64 + rowsum + q.ksp ; out = (vsp + oacc) / den
  const float* vsp = vspref + (size_t)blk * D_DIM;
#pragma unroll
  for (int r = 0; r < 4; ++r) {
    const int row = wave * 16 + quad * 4 + r;  // chunk-local t
    const float den = (float)(c * L_CHK) + rs[r] + kacc[r];
    const float inv = 1.f / den;
    const size_t ybase = (size_t)(t0 + row) * (H_NUM * D_DIM) + h * D_DIM;
#pragma unroll
    for (int et = 0; et < 4; ++et) {
      const int e = et * 16 + lrow;
      const float num = oacc[et][r] + vsp[e];
      yh[ybase + e] = (_Float16)(num * inv);
    }
  }
}

// ---------------------------------------------------------------------------
extern "C" void kernel_launch(void* const* d_in, const int* in_sizes, int n_in,
                              void* d_out, int out_size, void* d_ws,
                              size_t ws_size, hipStream_t stream) {
  const float* x = (const float*)d_in[0];       // (1,2048,1024)
  const float* w_attn = (const float*)d_in[1];  // (3072,1024)
  const float* w_proj = (const float*)d_in[2];  // (1024,1024)
  const float* cosb = (const float*)d_in[3];    // (2048,64)
  const float* sinb = (const float*)d_in[4];    // (2048,64)
  float* out = (float*)d_out;                   // (2048,1024)

  char* ws = (char*)d_ws;
  const size_t MB = 1048576;
  // 0..16MB: kvchunk (kvT layout), kvpref
  float* kvchunk = (float*)ws;
  float* kvpref = (float*)(ws + 8 * MB);
  // 16..48MB: fp16 hi/lo q,k (t,d) ; kT,vT (d/e, t)
  _Float16* qh = (_Float16*)(ws + 16 * MB);
  _Float16* ql = (_Float16*)(ws + 20 * MB);
  _Float16* kh = (_Float16*)(ws + 24 * MB);
  _Float16* kl = (_Float16*)(ws + 28 * MB);
  _Float16* kTh = (_Float16*)(ws + 32 * MB);
  _Float16* kTl = (_Float16*)(ws + 36 * MB);
  _Float16* vTh = (_Float16*)(ws + 40 * MB);
  _Float16* vTl = (_Float16*)(ws + 44 * MB);
  // 48..56MB: xh/xl (live split->QKV GEMM); then yh.
  _Float16* xh = (_Float16*)(ws + 48 * MB);
  _Float16* xl = (_Float16*)(ws + 52 * MB);
  _Float16* yh = (_Float16*)(ws + 48 * MB);
  // 56..68MB: wah/wal (live split->QKV GEMM); then scan vectors.
  _Float16* wah = (_Float16*)(ws + 56 * MB);
  _Float16* wal = (_Float16*)(ws + 62 * MB);
  float* kschunk = (float*)(ws + 56 * MB);
  float* vschunk = (float*)(ws + 56 * MB + 131072);
  float* kspref = (float*)(ws + 56 * MB + 262144);
  float* vspref = (float*)(ws + 56 * MB + 393216);
  // 68..70MB: wph (live whole call).
  _Float16* wph = (_Float16*)(ws + 68 * MB);

  // 0) fused splits (scale 64, undone in epilogues); w_proj hi-only
  split3_f16<<<3072, 256, 0, stream>>>(x, xh, xl, w_attn, wah, wal, w_proj,
                                       wph);

  // 1) qkv GEMM (f16x3, BK=64, 128x128 m97-geometry) + fused RoPE
  {
    dim3 grid(QKV_N / 128, T_LEN / 128);   // 24 x 16 = 384 blocks
    gemm_nt_f16<128, 128, true, true><<<grid, 256, 0, stream>>>(
        xh, xl, wah, wal, nullptr, cosb, sinb, qh, ql, kh, kl, kTh, kTl, vTh,
        vTl, T_LEN, QKV_N, C_DIM, 1.f / 4096.f);
  }
  // 2) per-chunk KV^T + ksum/vsum via MFMA
  chunk_kvT<<<H_NUM * NC, 256, 0, stream>>>(kTh, kTl, vTh, vTl, kvchunk,
                                            kschunk, vschunk);
  // 3) fused prefix scans (256 blocks kv + 4 blocks vec)
  scan_fused<<<260, 256, 0, stream>>>(kvchunk, kvpref, kschunk, vschunk,
                                      kspref, vspref);
  // 4) MFMA attention output -> yh (T, H*D) fp16
  attn_mfma<<<H_NUM * NC, 256, 0, stream>>>(qh, ql, kh, kl, vTh, vTl, kvpref,
                                            kspref, vspref, yh);
  // 5) out = y @ w_proj^T (plain fp16, BK=64, swizzled): 2^-6
  {
    dim3 grid(C_DIM / 64, T_LEN / 64);    // 16 x 32 = 512 blocks
    gemm_nt_f16<64, 64, false, false><<<grid, 256, 0, stream>>>(
        yh, nullptr, wph, nullptr, out, nullptr, nullptr, nullptr, nullptr,
        nullptr, nullptr, nullptr, nullptr, nullptr, nullptr, T_LEN, C_DIM,
        C_DIM, 1.f / 64.f);
  }
}

// Round 6
// 161.195 us; speedup vs baseline: 1.0443x; 1.0443x over previous
//
#include <hip/hip_runtime.h>

// Problem constants (B=1)
#define T_LEN 2048
#define C_DIM 1024
#define H_NUM 16
#define D_DIM 64
#define QKV_N (3 * H_NUM * D_DIM)   // 3072
#define L_CHK 64
#define NC (T_LEN / L_CHK)          // 32

typedef _Float16 h8 __attribute__((ext_vector_type(8)));
typedef _Float16 h4 __attribute__((ext_vector_type(4)));
typedef float f32x4 __attribute__((ext_vector_type(4)));

// ---------------------------------------------------------------------------
// Fused fp32 -> fp16 split, scale 64. x & w_attn get hi+lo; w_proj hi only.
// ---------------------------------------------------------------------------
__global__ __launch_bounds__(256) void split3_f16(
    const float* __restrict__ x, _Float16* __restrict__ xh,
    _Float16* __restrict__ xl, const float* __restrict__ wa,
    _Float16* __restrict__ wah, _Float16* __restrict__ wal,
    const float* __restrict__ wp, _Float16* __restrict__ wph) {
  int i = (blockIdx.x * 256 + threadIdx.x) * 8;
  const float* src;
  _Float16 *dh, *dl = nullptr;
  int base;
  if (i < 2097152) {
    src = x; dh = xh; dl = xl; base = i;
  } else if (i < 2097152 + 3145728) {
    src = wa; dh = wah; dl = wal; base = i - 2097152;
  } else {
    src = wp; dh = wph; base = i - 5242880;
  }
  float4 a = *(const float4*)(src + base);
  float4 b = *(const float4*)(src + base + 4);
  float v[8] = {a.x, a.y, a.z, a.w, b.x, b.y, b.z, b.w};
  h8 hv, lv;
#pragma unroll
  for (int j = 0; j < 8; ++j) {
    float s = v[j] * 64.f;
    _Float16 h = (_Float16)s;
    hv[j] = h;
    lv[j] = (_Float16)(s - (float)h);
  }
  *(h8*)(dh + base) = hv;
  if (dl) *(h8*)(dl + base) = lv;
}

// fp32 octet -> fp16 hi/lo fragments (den-critical paths)
__device__ __forceinline__ void split8(float4 a, float4 b, h8& hi, h8& lo) {
  float v[8] = {a.x, a.y, a.z, a.w, b.x, b.y, b.z, b.w};
#pragma unroll
  for (int m = 0; m < 8; ++m) {
    _Float16 hh = (_Float16)v[m];
    hi[m] = hh;
    lo[m] = (_Float16)(v[m] - (float)hh);
  }
}

// ---------------------------------------------------------------------------
// fp16 NT MFMA GEMM, BK=64, XOR-swizzled LDS (16B-block granularity).
// SPLIT3: acc += Ah*Bh + Ah*Bl + Al*Bh (fp32-grade). !SPLIT3: 1 MFMA.
// Tile BM=64 x BN, 256 thr = 2x2 waves of 32 x BN/2.
// ROPE epilogue (BN=128): wave's 64-col span == one q/k/v 64-dim block of
// one head. Outputs (error-budget-driven; den-paths fp32-grade):
//   q:(t,d) hi+lo   k:(t,d) hi+lo AND (d,t) hi+lo   v:(e,t) hi ONLY.
// cos/sin deduped [64][36]-stride tables (16B-aligned, 2-way-conflict=free);
// transposed stores via single-phase dual-region 32 KB bounce (XOR d^t).
// ---------------------------------------------------------------------------
template <int BN, bool ROPE, bool SPLIT3>
__global__ __launch_bounds__(256) void gemm_nt_f16(
    const _Float16* __restrict__ Ah, const _Float16* __restrict__ Al,
    const _Float16* __restrict__ Bh, const _Float16* __restrict__ Bl,
    float* __restrict__ C, const float* __restrict__ cosb,
    const float* __restrict__ sinb, _Float16* __restrict__ qh_,
    _Float16* __restrict__ ql_, _Float16* __restrict__ kh_,
    _Float16* __restrict__ kl_, _Float16* __restrict__ kTh_,
    _Float16* __restrict__ kTl_, _Float16* __restrict__ vTh_,
    int M, int N, int K, float outscale) {
  constexpr int NJ = BN / 32;  // N-tiles per wave
  constexpr int NARR = SPLIT3 ? 2 : 1;
  constexpr int GEMM_BYTES = (64 * 64 * 2 + BN * 64 * 2) * NARR;
  constexpr int ROPE_BYTES = ROPE ? (2 * 64 * 36 * 4 + 2 * 64 * 64 * 4) : 0;
  constexpr int SMEM_BYTES = GEMM_BYTES > ROPE_BYTES ? GEMM_BYTES : ROPE_BYTES;
  __shared__ __align__(16) char smem[SMEM_BYTES];
  _Float16* sAh = (_Float16*)smem;
  _Float16* sAl = sAh + 64 * 64;                       // SPLIT3 only
  _Float16* sBh = sAh + 64 * 64 * NARR;
  _Float16* sBl = sBh + BN * 64;                       // SPLIT3 only
  const int tid = threadIdx.x;
  const int wave = tid >> 6;
  const int lane = tid & 63;
  const int bm = blockIdx.y * 64;
  const int bn = blockIdx.x * BN;
  const int wm = wave >> 1;          // 0..1 -> 32-row half
  const int wn = wave & 1;           // 0..1 -> BN/2-col half
  const int srow = lane >> 3;        // 0..7 staging row within chunk
  const int sblk = ((lane & 7) ^ srow) * 8;  // swizzled col block (halves)
  const int quad = lane >> 4;        // 0..3
  const int lrow = lane & 15;

  f32x4 acc[2][NJ];
#pragma unroll
  for (int i = 0; i < 2; ++i)
#pragma unroll
    for (int j = 0; j < NJ; ++j) acc[i][j] = (f32x4){0.f, 0.f, 0.f, 0.f};

  for (int k0 = 0; k0 < K; k0 += 64) {
#pragma unroll
    for (int it = 0; it < 2; ++it) {
      const int ch = wave + it * 4;  // 0..7
      const int row = ch * 8 + srow;
      const _Float16* ga = Ah + (size_t)(bm + row) * K + k0 + sblk;
      __builtin_amdgcn_global_load_lds(
          (const __attribute__((address_space(1))) void*)ga,
          (__attribute__((address_space(3))) void*)(sAh + ch * 512), 16, 0, 0);
      if constexpr (SPLIT3) {
        const _Float16* gb = Al + (size_t)(bm + row) * K + k0 + sblk;
        __builtin_amdgcn_global_load_lds(
            (const __attribute__((address_space(1))) void*)gb,
            (__attribute__((address_space(3))) void*)(sAl + ch * 512), 16, 0,
            0);
      }
    }
#pragma unroll
    for (int it = 0; it < BN / 32; ++it) {
      const int ch = wave + it * 4;  // 0..BN/8-1
      const int row = ch * 8 + srow;
      const _Float16* ga = Bh + (size_t)(bn + row) * K + k0 + sblk;
      __builtin_amdgcn_global_load_lds(
          (const __attribute__((address_space(1))) void*)ga,
          (__attribute__((address_space(3))) void*)(sBh + ch * 512), 16, 0, 0);
      if constexpr (SPLIT3) {
        const _Float16* gb = Bl + (size_t)(bn + row) * K + k0 + sblk;
        __builtin_amdgcn_global_load_lds(
            (const __attribute__((address_space(1))) void*)gb,
            (__attribute__((address_space(3))) void*)(sBl + ch * 512), 16, 0,
            0);
      }
    }
    __syncthreads();
#pragma unroll
    for (int kk = 0; kk < 2; ++kk) {
      h8 ah[2], al[2], bh[NJ], bl[NJ];
#pragma unroll
      for (int i = 0; i < 2; ++i) {
        const int row = wm * 32 + i * 16 + lrow;
        const int ra = row * 64 + (((kk * 4 + quad) ^ (row & 7)) * 8);
        ah[i] = *(const h8*)&sAh[ra];
        if constexpr (SPLIT3) al[i] = *(const h8*)&sAl[ra];
      }
#pragma unroll
      for (int j = 0; j < NJ; ++j) {
        const int row = wn * (BN / 2) + j * 16 + lrow;
        const int rb = row * 64 + (((kk * 4 + quad) ^ (row & 7)) * 8);
        bh[j] = *(const h8*)&sBh[rb];
        if constexpr (SPLIT3) bl[j] = *(const h8*)&sBl[rb];
      }
#pragma unroll
      for (int i = 0; i < 2; ++i)
#pragma unroll
        for (int j = 0; j < NJ; ++j) {
          acc[i][j] = __builtin_amdgcn_mfma_f32_16x16x32_f16(
              ah[i], bh[j], acc[i][j], 0, 0, 0);
          if constexpr (SPLIT3) {
            acc[i][j] = __builtin_amdgcn_mfma_f32_16x16x32_f16(
                ah[i], bl[j], acc[i][j], 0, 0, 0);
            acc[i][j] = __builtin_amdgcn_mfma_f32_16x16x32_f16(
                al[i], bh[j], acc[i][j], 0, 0, 0);
          }
        }
    }
    __syncthreads();
  }
  // epilogue: C/D layout col=lane&15, row=quad*4+reg
  if constexpr (!ROPE) {
#pragma unroll
    for (int i = 0; i < 2; ++i) {
      const int rbase = bm + wm * 32 + i * 16 + quad * 4;
#pragma unroll
      for (int j = 0; j < NJ; ++j) {
        const int col = bn + wn * (BN / 2) + j * 16 + lrow;
#pragma unroll
        for (int r = 0; r < 4; ++r)
          C[(size_t)(rbase + r) * N + col] = acc[i][j][r] * outscale;
      }
    }
  } else {
    float* cs = (float*)smem;        // [64][36] deduped cos (9 KB)
    float* sn = cs + 2304;           // [64][36] deduped sin (9 KB)
    float* bounce = sn + 2304;       // 2 x 4096 fp32 = 32 KB
    {
      const int el = tid * 8;        // 2048 payload floats, 8 per thread
      const int t = el >> 5, d0 = el & 31;
      const float* gc = &cosb[(size_t)(bm + t) * D_DIM + d0];
      const float* gs = &sinb[(size_t)(bm + t) * D_DIM + d0];
      *(float4*)&cs[t * 36 + d0] = *(const float4*)gc;
      *(float4*)&cs[t * 36 + d0 + 4] = *(const float4*)(gc + 4);
      *(float4*)&sn[t * 36 + d0] = *(const float4*)gs;
      *(float4*)&sn[t * 36 + d0 + 4] = *(const float4*)(gs + 4);
    }
    __syncthreads();
    const int colbase = bn + wn * 64;
    const int type = (colbase >> 6) % 3;    // 0=q, 1=k, 2=v
    const int head = colbase / 192;
    const size_t hb = (size_t)head * T_LEN * D_DIM;
    // final fp32 values (rope applied for q/k), fv[i][reg][j]
    float fv[2][4][4];
#pragma unroll
    for (int i = 0; i < 2; ++i)
#pragma unroll
      for (int r = 0; r < 4; ++r) {
        const int tloc = wm * 32 + i * 16 + quad * 4 + r;
#pragma unroll
        for (int j = 0; j < 4; ++j) {
          const int d32 = (j & 1) * 16 + lrow;   // d mod 32
          float val = acc[i][j][r] * outscale;
          if (type < 2) {
            float rotv =
                ((j < 2) ? -acc[i][j + 2][r] : acc[i][j - 2][r]) * outscale;
            val = val * cs[tloc * 36 + d32] + rotv * sn[tloc * 36 + d32];
          }
          fv[i][r][j] = val;
        }
      }
    // direct (t,d) fp16 hi/lo stores for q and k (den-critical: keep split)
    if (type < 2) {
      _Float16* dh = (type == 0 ? qh_ : kh_) + hb;
      _Float16* dl = (type == 0 ? ql_ : kl_) + hb;
#pragma unroll
      for (int i = 0; i < 2; ++i)
#pragma unroll
        for (int r = 0; r < 4; ++r) {
          const size_t trow =
              (size_t)(bm + wm * 32 + i * 16 + quad * 4 + r) * D_DIM;
#pragma unroll
          for (int j = 0; j < 4; ++j) {
            const int d = j * 16 + lrow;
            float f = fv[i][r][j];
            _Float16 hh = (_Float16)f;
            dh[trow + d] = hh;
            dl[trow + d] = (_Float16)(f - (float)hh);
          }
        }
    }
    // transposed (d,t) stores: k hi+lo (ksum is den-critical), v hi only.
    const bool doT = (type >= 1);
    _Float16* th = (type == 1 ? kTh_ : vTh_) + hb;
    _Float16* tl = kTl_ + hb;        // used only when type == 1
    float* myb = bounce + wn * 4096;
    if (doT) {
#pragma unroll
      for (int i = 0; i < 2; ++i)
#pragma unroll
        for (int r = 0; r < 4; ++r) {
          const int tloc = wm * 32 + i * 16 + quad * 4 + r;
#pragma unroll
          for (int j = 0; j < 4; ++j) {
            const int d = j * 16 + lrow;
            myb[tloc * 64 + (d ^ tloc)] = fv[i][r][j];
          }
        }
    }
    __syncthreads();
    if (doT) {
      const int lt = wm * 64 + lane;   // 0..127 over the 2 same-wn waves
      const int e = lt >> 1;           // output row (dim)
      const int tg0 = (lt & 1) * 32;   // 32-t half
#pragma unroll
      for (int s8 = 0; s8 < 4; ++s8) {
        h8 hv, lv;
#pragma unroll
        for (int s = 0; s < 8; ++s) {
          const int t = tg0 + s8 * 8 + s;
          float f = myb[t * 64 + (e ^ t)];
          _Float16 hh = (_Float16)f;
          hv[s] = hh;
          lv[s] = (_Float16)(f - (float)hh);
        }
        *(h8*)&th[(size_t)e * T_LEN + bm + tg0 + s8 * 8] = hv;
        if (type == 1)
          *(h8*)&tl[(size_t)e * T_LEN + bm + tg0 + s8 * 8] = lv;
      }
    }
  }
}

// ---------------------------------------------------------------------------
// Per-(head,chunk) KV^T via MFMA: kvT[e][d] = sum_t v[t][e]*k[t][d].
// kv product is num-path -> hi*hi only (8 MFMAs). ksum (den-path) uses
// kTh+kTl exactly; vsum (num-path) hi only. Global-direct frags, no LDS.
// ---------------------------------------------------------------------------
__global__ __launch_bounds__(256) void chunk_kvT(
    const _Float16* __restrict__ kTh, const _Float16* __restrict__ kTl,
    const _Float16* __restrict__ vTh, float* __restrict__ kvchunk,
    float* __restrict__ kschunk, float* __restrict__ vschunk) {
  const int blk = blockIdx.x;  // h*NC + c
  const int h = blk / NC, c = blk % NC;
  const int tid = threadIdx.x;
  const int wave = tid >> 6, lane = tid & 63;
  const int quad = lane >> 4, lrow = lane & 15;
  const size_t hb = (size_t)h * D_DIM * T_LEN;
  const int tb = c * L_CHK;
  // A-frags: vT rows e = wave*16+lrow, t-range = ks*32 + quad*8
  h8 avh[2];
  {
    const _Float16* pa = vTh + hb + (size_t)(wave * 16 + lrow) * T_LEN + tb +
                         quad * 8;
    avh[0] = *(const h8*)pa;
    avh[1] = *(const h8*)(pa + 32);
  }
  f32x4 accv[4];
#pragma unroll
  for (int dt = 0; dt < 4; ++dt) accv[dt] = (f32x4){0.f, 0.f, 0.f, 0.f};
#pragma unroll
  for (int dt = 0; dt < 4; ++dt) {
    const _Float16* pb = kTh + hb + (size_t)(dt * 16 + lrow) * T_LEN + tb +
                         quad * 8;
#pragma unroll
    for (int ks = 0; ks < 2; ++ks) {
      h8 bh = *(const h8*)(pb + ks * 32);
      accv[dt] = __builtin_amdgcn_mfma_f32_16x16x32_f16(avh[ks], bh, accv[dt],
                                                        0, 0, 0);
    }
  }
  // store kvT: row e = wave*16 + quad*4 + reg, col d = dt*16 + lrow
  float* ob = kvchunk + (size_t)blk * (D_DIM * D_DIM);
#pragma unroll
  for (int dt = 0; dt < 4; ++dt)
#pragma unroll
    for (int r = 0; r < 4; ++r)
      ob[(wave * 16 + quad * 4 + r) * D_DIM + dt * 16 + lrow] = accv[dt][r];
  // ksum (exact hi+lo, den-path) / vsum (hi, num-path)
  if (tid < 64) {
    const _Float16* p = kTh + hb + (size_t)tid * T_LEN + tb;
    const _Float16* pl = kTl + hb + (size_t)tid * T_LEN + tb;
    float s = 0.f;
#pragma unroll
    for (int i = 0; i < 8; ++i) {
      h8 a = *(const h8*)(p + i * 8), b = *(const h8*)(pl + i * 8);
#pragma unroll
      for (int m = 0; m < 8; ++m) s += (float)a[m] + (float)b[m];
    }
    kschunk[(size_t)blk * D_DIM + tid] = s;
  } else if (tid < 128) {
    const int e = tid - 64;
    const _Float16* p = vTh + hb + (size_t)e * T_LEN + tb;
    float s = 0.f;
#pragma unroll
    for (int i = 0; i < 8; ++i) {
      h8 a = *(const h8*)(p + i * 8);
#pragma unroll
      for (int m = 0; m < 8; ++m) s += (float)a[m];
    }
    vschunk[(size_t)blk * D_DIM + e] = s;
  }
}

// ---------------------------------------------------------------------------
// Fused exclusive prefix scans over chunks. kv state accumulates fp32 but is
// EMITTED as fp16 (num-path tolerance) -> halves attn's kvpref traffic and
// removes its in-kernel fp32->fp16 conversion. Vectors stay fp32 (den-path).
// ---------------------------------------------------------------------------
__global__ __launch_bounds__(256) void scan_fused(
    const float* __restrict__ kvchunk, _Float16* __restrict__ kvph,
    const float* __restrict__ kschunk, const float* __restrict__ vschunk,
    float* __restrict__ kspref, float* __restrict__ vspref) {
  int b = blockIdx.x;
  int tid = threadIdx.x;
  if (b < 256) {
    int gid = b * 256 + tid;  // h*4096 + de
    int h = gid >> 12;
    int de = gid & 4095;
    float vals[NC];
#pragma unroll
    for (int c = 0; c < NC; ++c)
      vals[c] = kvchunk[((size_t)(h * NC + c) << 12) + de];
    float run = 0.f;
#pragma unroll
    for (int c = 0; c < NC; ++c) {
      kvph[((size_t)(h * NC + c) << 12) + de] = (_Float16)run;
      run += vals[c];
    }
  } else {
    int gid = (b - 256) * 256 + tid;  // h*64 + d (total 1024)
    int h = gid >> 6, d = gid & 63;
    float kv_[NC], vv_[NC];
#pragma unroll
    for (int c = 0; c < NC; ++c) {
      size_t idx = (size_t)(h * NC + c) * 64 + d;
      kv_[c] = kschunk[idx];
      vv_[c] = vschunk[idx];
    }
    float rk = 0.f, rv = 0.f;
#pragma unroll
    for (int c = 0; c < NC; ++c) {
      size_t idx = (size_t)(h * NC + c) * 64 + d;
      kspref[idx] = rk;
      vspref[idx] = rv;
      rk += kv_[c];
      rv += vv_[c];
    }
  }
}

// ---------------------------------------------------------------------------
// MFMA attention output. One block per (h,c), 4 waves; wave w owns rows
// [w*16, w*16+16) x all 64 e-cols.
//   S = Q K^T split3 (den-critical) -> mask/+1 -> fp16 hi/lo wave-private
//   swizzled LDS; rowsum via ones-MFMA on Sh+Sl (den); S.V = (Sh+Sl).Vh;
//   q.KVpref = qh.KVh (num, fp16 direct); q.kspref split3 (den).
// No __syncthreads (all LDS wave-private).
// ---------------------------------------------------------------------------
__global__ __launch_bounds__(256) void attn_mfma(
    const _Float16* __restrict__ qh, const _Float16* __restrict__ ql,
    const _Float16* __restrict__ kh, const _Float16* __restrict__ kl,
    const _Float16* __restrict__ vTh, const _Float16* __restrict__ kvph,
    const float* __restrict__ kspref, const float* __restrict__ vspref,
    _Float16* __restrict__ yh) {
  __shared__ __align__(16) _Float16 sS[2][4][16 * 64];  // [plane][wave][r*64+j]
  const int blk = blockIdx.x;  // h*NC + c
  const int h = blk / NC, c = blk % NC;
  const int tid = threadIdx.x;
  const int wave = tid >> 6, lane = tid & 63;
  const int quad = lane >> 4, lrow = lane & 15;
  const size_t hb = (size_t)h * T_LEN * D_DIM;   // (t,d) arrays
  const size_t hbT = (size_t)h * D_DIM * T_LEN;  // (e,t) arrays
  const int t0 = c * L_CHK;
  const f32x4 z4 = {0.f, 0.f, 0.f, 0.f};
  // Q A-frags: rows t0 + wave*16 + lrow, d-range ks*32 + quad*8
  h8 aqh[2], aql[2];
  {
    const _Float16* pq =
        qh + hb + (size_t)(t0 + wave * 16 + lrow) * D_DIM + quad * 8;
    const _Float16* pql =
        ql + hb + (size_t)(t0 + wave * 16 + lrow) * D_DIM + quad * 8;
    aqh[0] = *(const h8*)pq;
    aqh[1] = *(const h8*)(pq + 32);
    aql[0] = *(const h8*)pql;
    aql[1] = *(const h8*)(pql + 32);
  }
  // Phase 1: S = Q K^T (within-chunk), 4 col-tiles, split3 (den-critical)
  f32x4 sacc[4];
#pragma unroll
  for (int jt = 0; jt < 4; ++jt) sacc[jt] = z4;
#pragma unroll
  for (int jt = 0; jt < 4; ++jt) {
    const _Float16* pk =
        kh + hb + (size_t)(t0 + jt * 16 + lrow) * D_DIM + quad * 8;
    const _Float16* pkl =
        kl + hb + (size_t)(t0 + jt * 16 + lrow) * D_DIM + quad * 8;
#pragma unroll
    for (int ks = 0; ks < 2; ++ks) {
      h8 bh = *(const h8*)(pk + ks * 32);
      h8 bl = *(const h8*)(pkl + ks * 32);
      sacc[jt] = __builtin_amdgcn_mfma_f32_16x16x32_f16(aqh[ks], bh, sacc[jt],
                                                        0, 0, 0);
      sacc[jt] = __builtin_amdgcn_mfma_f32_16x16x32_f16(aqh[ks], bl, sacc[jt],
                                                        0, 0, 0);
      sacc[jt] = __builtin_amdgcn_mfma_f32_16x16x32_f16(aql[ks], bh, sacc[jt],
                                                        0, 0, 0);
    }
  }
  // mask, +1, fp16 split, stage (swizzled: 8-half blocks XOR'd by row&7)
  _Float16* shp = &sS[0][wave][0];
  _Float16* slp = &sS[1][wave][0];
#pragma unroll
  for (int jt = 0; jt < 4; ++jt)
#pragma unroll
    for (int r = 0; r < 4; ++r) {
      const int row = quad * 4 + r;          // band-local row
      const int j = jt * 16 + lrow;          // chunk-local col
      const int rglob = wave * 16 + row;
      float s = (j <= rglob) ? (sacc[jt][r] + 1.f) : 0.f;
      _Float16 hh = (_Float16)s;
      const int adr = row * 64 + ((((j >> 3) ^ (row & 7)) << 3) | (j & 7));
      shp[adr] = hh;
      slp[adr] = (_Float16)(s - (float)hh);
    }
  // S A-frags (own band, same-wave LDS dependency)
  h8 ash[2], asl[2];
#pragma unroll
  for (int ks = 0; ks < 2; ++ks) {
    const int adr = lrow * 64 + (((ks * 4 + quad) ^ (lrow & 7)) << 3);
    ash[ks] = *(const h8*)&shp[adr];
    asl[ks] = *(const h8*)&slp[adr];
  }
  // rowsum(S) via ones-fragment (exact: Sh+Sl; den-critical)
  h8 ones;
#pragma unroll
  for (int m = 0; m < 8; ++m) ones[m] = (_Float16)1.0f;
  f32x4 rs = z4;
#pragma unroll
  for (int ks = 0; ks < 2; ++ks) {
    rs = __builtin_amdgcn_mfma_f32_16x16x32_f16(ash[ks], ones, rs, 0, 0, 0);
    rs = __builtin_amdgcn_mfma_f32_16x16x32_f16(asl[ks], ones, rs, 0, 0, 0);
  }
  // out accumulation: S.V = (Sh+Sl).Vh (num-path)
  f32x4 oacc[4];
#pragma unroll
  for (int et = 0; et < 4; ++et) oacc[et] = z4;
#pragma unroll
  for (int et = 0; et < 4; ++et) {
    const _Float16* pv =
        vTh + hbT + (size_t)(et * 16 + lrow) * T_LEN + t0 + quad * 8;
#pragma unroll
    for (int ks = 0; ks < 2; ++ks) {
      h8 bh = *(const h8*)(pv + ks * 32);
      oacc[et] = __builtin_amdgcn_mfma_f32_16x16x32_f16(ash[ks], bh, oacc[et],
                                                        0, 0, 0);
      oacc[et] = __builtin_amdgcn_mfma_f32_16x16x32_f16(asl[ks], bh, oacc[et],
                                                        0, 0, 0);
    }
  }
  // q . KVpref (num-path, fp16 direct)
  const _Float16* kvp = kvph + ((size_t)blk << 12);
#pragma unroll
  for (int et = 0; et < 4; ++et) {
#pragma unroll
    for (int ks = 0; ks < 2; ++ks) {
      h8 bh = *(const h8*)&kvp[(et * 16 + lrow) * D_DIM + ks * 32 + quad * 8];
      oacc[et] = __builtin_amdgcn_mfma_f32_16x16x32_f16(aqh[ks], bh, oacc[et],
                                                        0, 0, 0);
    }
  }
  // den extra: q . kspref split3 via broadcast fragment (den-critical)
  const float* ksp = kspref + (size_t)blk * D_DIM;
  f32x4 kacc = z4;
#pragma unroll
  for (int ks = 0; ks < 2; ++ks) {
    const float* pb = ksp + ks * 32 + quad * 8;
    float4 b0 = *(const float4*)pb;
    float4 b1 = *(const float4*)(pb + 4);
    h8 bh, bl;
    split8(b0, b1, bh, bl);
    kacc = __builtin_amdgcn_mfma_f32_16x16x32_f16(aqh[ks], bh, kacc, 0, 0, 0);
    kacc = __builtin_amdgcn_mfma_f32_16x16x32_f16(aqh[ks], bl, kacc, 0, 0, 0);
    kacc = __builtin_amdgcn_mfma_f32_16x16x32_f16(aql[ks], bh, kacc, 0, 0, 0);
  }
  // epilogue: den = c*64 + rowsum + q.ksp ; out = (vsp + oacc) / den
  const float* vsp = vspref + (size_t)blk * D_DIM;
#pragma unroll
  for (int r = 0; r < 4; ++r) {
    const int row = wave * 16 + quad * 4 + r;  // chunk-local t
    const float den = (float)(c * L_CHK) + rs[r] + kacc[r];
    const float inv = 1.f / den;
    const size_t ybase = (size_t)(t0 + row) * (H_NUM * D_DIM) + h * D_DIM;
#pragma unroll
    for (int et = 0; et < 4; ++et) {
      const int e = et * 16 + lrow;
      const float num = oacc[et][r] + vsp[e];
      yh[ybase + e] = (_Float16)(num * inv);
    }
  }
}

// ---------------------------------------------------------------------------
extern "C" void kernel_launch(void* const* d_in, const int* in_sizes, int n_in,
                              void* d_out, int out_size, void* d_ws,
                              size_t ws_size, hipStream_t stream) {
  const float* x = (const float*)d_in[0];       // (1,2048,1024)
  const float* w_attn = (const float*)d_in[1];  // (3072,1024)
  const float* w_proj = (const float*)d_in[2];  // (1024,1024)
  const float* cosb = (const float*)d_in[3];    // (2048,64)
  const float* sinb = (const float*)d_in[4];    // (2048,64)
  float* out = (float*)d_out;                   // (2048,1024)

  char* ws = (char*)d_ws;
  const size_t MB = 1048576;
  // 0..8MB: kvchunk fp32; 8..12MB: kvph fp16 prefix
  float* kvchunk = (float*)ws;
  _Float16* kvph = (_Float16*)(ws + 8 * MB);
  // 16..44MB: fp16 q,k hi/lo (t,d); kT hi/lo, vT hi (d/e, t)
  _Float16* qh = (_Float16*)(ws + 16 * MB);
  _Float16* ql = (_Float16*)(ws + 20 * MB);
  _Float16* kh = (_Float16*)(ws + 24 * MB);
  _Float16* kl = (_Float16*)(ws + 28 * MB);
  _Float16* kTh = (_Float16*)(ws + 32 * MB);
  _Float16* kTl = (_Float16*)(ws + 36 * MB);
  _Float16* vTh = (_Float16*)(ws + 40 * MB);
  // 48..56MB: xh/xl (live split->QKV GEMM); then yh.
  _Float16* xh = (_Float16*)(ws + 48 * MB);
  _Float16* xl = (_Float16*)(ws + 52 * MB);
  _Float16* yh = (_Float16*)(ws + 48 * MB);
  // 56..68MB: wah/wal (live split->QKV GEMM); then scan vectors.
  _Float16* wah = (_Float16*)(ws + 56 * MB);
  _Float16* wal = (_Float16*)(ws + 62 * MB);
  float* kschunk = (float*)(ws + 56 * MB);
  float* vschunk = (float*)(ws + 56 * MB + 131072);
  float* kspref = (float*)(ws + 56 * MB + 262144);
  float* vspref = (float*)(ws + 56 * MB + 393216);
  // 68..70MB: wph (live whole call).
  _Float16* wph = (_Float16*)(ws + 68 * MB);

  // 0) fused splits (scale 64, undone in epilogues); w_proj hi-only
  split3_f16<<<3072, 256, 0, stream>>>(x, xh, xl, w_attn, wah, wal, w_proj,
                                       wph);

  // 1) qkv GEMM (f16x3, BK=64, swizzled) + fused RoPE
  {
    dim3 grid(QKV_N / 128, T_LEN / 64);   // 24 x 32 = 768 blocks
    gemm_nt_f16<128, true, true><<<grid, 256, 0, stream>>>(
        xh, xl, wah, wal, nullptr, cosb, sinb, qh, ql, kh, kl, kTh, kTl, vTh,
        T_LEN, QKV_N, C_DIM, 1.f / 4096.f);
  }
  // 2) per-chunk KV^T (hi*hi) + exact ksum / hi vsum
  chunk_kvT<<<H_NUM * NC, 256, 0, stream>>>(kTh, kTl, vTh, kvchunk, kschunk,
                                            vschunk);
  // 3) fused prefix scans (kv -> fp16; vectors fp32)
  scan_fused<<<260, 256, 0, stream>>>(kvchunk, kvph, kschunk, vschunk,
                                      kspref, vspref);
  // 4) MFMA attention output -> yh (T, H*D) fp16
  attn_mfma<<<H_NUM * NC, 256, 0, stream>>>(qh, ql, kh, kl, vTh, kvph,
                                            kspref, vspref, yh);
  // 5) out = y @ w_proj^T (plain fp16, BK=64, swizzled): 2^-6
  {
    dim3 grid(C_DIM / 64, T_LEN / 64);    // 16 x 32 = 512 blocks
    gemm_nt_f16<64, false, false><<<grid, 256, 0, stream>>>(
        yh, nullptr, wph, nullptr, out, nullptr, nullptr, nullptr, nullptr,
        nullptr, nullptr, nullptr, nullptr, nullptr, T_LEN, C_DIM, C_DIM,
        1.f / 64.f);
  }
}

// Round 7
// 159.108 us; speedup vs baseline: 1.0580x; 1.0131x over previous
//
#include <hip/hip_runtime.h>

// Problem constants (B=1)
#define T_LEN 2048
#define C_DIM 1024
#define H_NUM 16
#define D_DIM 64
#define QKV_N (3 * H_NUM * D_DIM)   // 3072
#define L_CHK 64
#define NC (T_LEN / L_CHK)          // 32

typedef _Float16 h8 __attribute__((ext_vector_type(8)));
typedef _Float16 h4 __attribute__((ext_vector_type(4)));
typedef float f32x4 __attribute__((ext_vector_type(4)));

// ---------------------------------------------------------------------------
// Fused fp32 -> fp16 split, scale 64. x & w_attn get hi+lo; w_proj hi only.
// ---------------------------------------------------------------------------
__global__ __launch_bounds__(256) void split3_f16(
    const float* __restrict__ x, _Float16* __restrict__ xh,
    _Float16* __restrict__ xl, const float* __restrict__ wa,
    _Float16* __restrict__ wah, _Float16* __restrict__ wal,
    const float* __restrict__ wp, _Float16* __restrict__ wph) {
  int i = (blockIdx.x * 256 + threadIdx.x) * 8;
  const float* src;
  _Float16 *dh, *dl = nullptr;
  int base;
  if (i < 2097152) {
    src = x; dh = xh; dl = xl; base = i;
  } else if (i < 2097152 + 3145728) {
    src = wa; dh = wah; dl = wal; base = i - 2097152;
  } else {
    src = wp; dh = wph; base = i - 5242880;
  }
  float4 a = *(const float4*)(src + base);
  float4 b = *(const float4*)(src + base + 4);
  float v[8] = {a.x, a.y, a.z, a.w, b.x, b.y, b.z, b.w};
  h8 hv, lv;
#pragma unroll
  for (int j = 0; j < 8; ++j) {
    float s = v[j] * 64.f;
    _Float16 h = (_Float16)s;
    hv[j] = h;
    lv[j] = (_Float16)(s - (float)h);
  }
  *(h8*)(dh + base) = hv;
  if (dl) *(h8*)(dl + base) = lv;
}

// fp32 octet -> fp16 hi/lo fragments (den-critical paths)
__device__ __forceinline__ void split8(float4 a, float4 b, h8& hi, h8& lo) {
  float v[8] = {a.x, a.y, a.z, a.w, b.x, b.y, b.z, b.w};
#pragma unroll
  for (int m = 0; m < 8; ++m) {
    _Float16 hh = (_Float16)v[m];
    hi[m] = hh;
    lo[m] = (_Float16)(v[m] - (float)hh);
  }
}

// ---------------------------------------------------------------------------
// fp16 NT MFMA GEMM, BK=64, XOR-swizzled LDS (16B-block granularity).
// SPLIT3: acc += Ah*Bh + Ah*Bl + Al*Bh (fp32-grade). !SPLIT3: 1 MFMA.
// Tile BM=64 x BN, 256 thr = 2x2 waves of 32 x BN/2.
// ROPE (QKV): blockIdx.x remapped so BOTH 64-col halves of a block are the
// SAME type (q/k/v) on two adjacent heads: bx 0..7=q, 8..15=k, 16..23=v;
// halves = heads 2*(bx&7), 2*(bx&7)+1. v-blocks are num-path-tolerant:
// hi*hi MFMAs only (16 vs 48 per wave/K-step) and no Al/Bl staging.
// Epilogue (block-uniform type): q -> direct hi/lo stores; k -> direct hi/lo
// + transposed hi/lo via bounce; v -> transposed hi via bounce.
// ---------------------------------------------------------------------------
template <int BN, bool ROPE, bool SPLIT3>
__global__ __launch_bounds__(256) void gemm_nt_f16(
    const _Float16* __restrict__ Ah, const _Float16* __restrict__ Al,
    const _Float16* __restrict__ Bh, const _Float16* __restrict__ Bl,
    float* __restrict__ C, const float* __restrict__ cosb,
    const float* __restrict__ sinb, _Float16* __restrict__ qh_,
    _Float16* __restrict__ ql_, _Float16* __restrict__ kh_,
    _Float16* __restrict__ kl_, _Float16* __restrict__ kTh_,
    _Float16* __restrict__ kTl_, _Float16* __restrict__ vTh_,
    int M, int N, int K, float outscale) {
  constexpr int NJ = BN / 32;  // N-tiles per wave
  constexpr int NARR = SPLIT3 ? 2 : 1;
  constexpr int GEMM_BYTES = (64 * 64 * 2 + BN * 64 * 2) * NARR;
  constexpr int ROPE_BYTES = ROPE ? (2 * 64 * 36 * 4 + 2 * 64 * 64 * 4) : 0;
  constexpr int SMEM_BYTES = GEMM_BYTES > ROPE_BYTES ? GEMM_BYTES : ROPE_BYTES;
  __shared__ __align__(16) char smem[SMEM_BYTES];
  _Float16* sAh = (_Float16*)smem;
  _Float16* sAl = sAh + 64 * 64;                       // SPLIT3 only
  _Float16* sBh = sAh + 64 * 64 * NARR;
  _Float16* sBl = sBh + BN * 64;                       // SPLIT3 only
  const int tid = threadIdx.x;
  const int wave = tid >> 6;
  const int lane = tid & 63;
  const int bm = blockIdx.y * 64;
  const int wm = wave >> 1;          // 0..1 -> 32-row half
  const int wn = wave & 1;           // 0..1 -> BN/2-col half
  const int srow = lane >> 3;        // 0..7 staging row within chunk
  const int sblk = ((lane & 7) ^ srow) * 8;  // swizzled col block (halves)
  const int quad = lane >> 4;        // 0..3
  const int lrow = lane & 15;

  // column-block mapping (units of 64 cols)
  int btype = -1, pi = 0, cb0, cb1;
  if constexpr (ROPE) {
    btype = blockIdx.x >> 3;         // 0=q 1=k 2=v (block-uniform)
    pi = blockIdx.x & 7;             // head pair index
    cb0 = (2 * pi) * 3 + btype;
    cb1 = (2 * pi + 1) * 3 + btype;
  } else {
    cb0 = blockIdx.x * (BN / 64);
    cb1 = cb0 + 1;
  }
  const bool isV = ROPE && (btype == 2);

  f32x4 acc[2][NJ];
#pragma unroll
  for (int i = 0; i < 2; ++i)
#pragma unroll
    for (int j = 0; j < NJ; ++j) acc[i][j] = (f32x4){0.f, 0.f, 0.f, 0.f};

  for (int k0 = 0; k0 < K; k0 += 64) {
#pragma unroll
    for (int it = 0; it < 2; ++it) {
      const int ch = wave + it * 4;  // 0..7
      const int row = ch * 8 + srow;
      const _Float16* ga = Ah + (size_t)(bm + row) * K + k0 + sblk;
      __builtin_amdgcn_global_load_lds(
          (const __attribute__((address_space(1))) void*)ga,
          (__attribute__((address_space(3))) void*)(sAh + ch * 512), 16, 0, 0);
      if constexpr (SPLIT3) {
        if (!isV) {
          const _Float16* gb = Al + (size_t)(bm + row) * K + k0 + sblk;
          __builtin_amdgcn_global_load_lds(
              (const __attribute__((address_space(1))) void*)gb,
              (__attribute__((address_space(3))) void*)(sAl + ch * 512), 16, 0,
              0);
        }
      }
    }
#pragma unroll
    for (int it = 0; it < BN / 32; ++it) {
      const int ch = wave + it * 4;  // 0..BN/8-1
      const int lr = ch * 8 + srow;  // 0..BN-1 local col-row
      const int grow = ((lr < 64) ? cb0 : cb1) * 64 + (lr & 63);
      const _Float16* ga = Bh + (size_t)grow * K + k0 + sblk;
      __builtin_amdgcn_global_load_lds(
          (const __attribute__((address_space(1))) void*)ga,
          (__attribute__((address_space(3))) void*)(sBh + ch * 512), 16, 0, 0);
      if constexpr (SPLIT3) {
        if (!isV) {
          const _Float16* gb = Bl + (size_t)grow * K + k0 + sblk;
          __builtin_amdgcn_global_load_lds(
              (const __attribute__((address_space(1))) void*)gb,
              (__attribute__((address_space(3))) void*)(sBl + ch * 512), 16, 0,
              0);
        }
      }
    }
    __syncthreads();
    if (SPLIT3 && !isV) {
#pragma unroll
      for (int kk = 0; kk < 2; ++kk) {
        h8 ah[2], al[2], bh[NJ], bl[NJ];
#pragma unroll
        for (int i = 0; i < 2; ++i) {
          const int row = wm * 32 + i * 16 + lrow;
          const int ra = row * 64 + (((kk * 4 + quad) ^ (row & 7)) * 8);
          ah[i] = *(const h8*)&sAh[ra];
          al[i] = *(const h8*)&sAl[ra];
        }
#pragma unroll
        for (int j = 0; j < NJ; ++j) {
          const int row = wn * (BN / 2) + j * 16 + lrow;
          const int rb = row * 64 + (((kk * 4 + quad) ^ (row & 7)) * 8);
          bh[j] = *(const h8*)&sBh[rb];
          bl[j] = *(const h8*)&sBl[rb];
        }
#pragma unroll
        for (int i = 0; i < 2; ++i)
#pragma unroll
          for (int j = 0; j < NJ; ++j) {
            acc[i][j] = __builtin_amdgcn_mfma_f32_16x16x32_f16(
                ah[i], bh[j], acc[i][j], 0, 0, 0);
            acc[i][j] = __builtin_amdgcn_mfma_f32_16x16x32_f16(
                ah[i], bl[j], acc[i][j], 0, 0, 0);
            acc[i][j] = __builtin_amdgcn_mfma_f32_16x16x32_f16(
                al[i], bh[j], acc[i][j], 0, 0, 0);
          }
      }
    } else {
#pragma unroll
      for (int kk = 0; kk < 2; ++kk) {
        h8 ah[2], bh[NJ];
#pragma unroll
        for (int i = 0; i < 2; ++i) {
          const int row = wm * 32 + i * 16 + lrow;
          const int ra = row * 64 + (((kk * 4 + quad) ^ (row & 7)) * 8);
          ah[i] = *(const h8*)&sAh[ra];
        }
#pragma unroll
        for (int j = 0; j < NJ; ++j) {
          const int row = wn * (BN / 2) + j * 16 + lrow;
          const int rb = row * 64 + (((kk * 4 + quad) ^ (row & 7)) * 8);
          bh[j] = *(const h8*)&sBh[rb];
        }
#pragma unroll
        for (int i = 0; i < 2; ++i)
#pragma unroll
          for (int j = 0; j < NJ; ++j)
            acc[i][j] = __builtin_amdgcn_mfma_f32_16x16x32_f16(
                ah[i], bh[j], acc[i][j], 0, 0, 0);
      }
    }
    __syncthreads();
  }
  // epilogue: C/D layout col=lane&15, row=quad*4+reg
  if constexpr (!ROPE) {
#pragma unroll
    for (int i = 0; i < 2; ++i) {
      const int rbase = bm + wm * 32 + i * 16 + quad * 4;
#pragma unroll
      for (int j = 0; j < NJ; ++j) {
        const int col = blockIdx.x * BN + wn * (BN / 2) + j * 16 + lrow;
#pragma unroll
        for (int r = 0; r < 4; ++r)
          C[(size_t)(rbase + r) * N + col] = acc[i][j][r] * outscale;
      }
    }
  } else {
    float* cs = (float*)smem;        // [64][36] deduped cos (9 KB)
    float* sn = cs + 2304;           // [64][36] deduped sin (9 KB)
    float* bounce = sn + 2304;       // 2 x 4096 fp32 = 32 KB
    if (btype < 2) {
      const int el = tid * 8;        // 2048 payload floats, 8 per thread
      const int t = el >> 5, d0 = el & 31;
      const float* gc = &cosb[(size_t)(bm + t) * D_DIM + d0];
      const float* gs = &sinb[(size_t)(bm + t) * D_DIM + d0];
      *(float4*)&cs[t * 36 + d0] = *(const float4*)gc;
      *(float4*)&cs[t * 36 + d0 + 4] = *(const float4*)(gc + 4);
      *(float4*)&sn[t * 36 + d0] = *(const float4*)gs;
      *(float4*)&sn[t * 36 + d0 + 4] = *(const float4*)(gs + 4);
    }
    __syncthreads();
    const int head = 2 * pi + wn;    // each wn half = one head, same type
    const size_t hb = (size_t)head * T_LEN * D_DIM;
    // final fp32 values (rope applied for q/k), fv[i][reg][j]
    float fv[2][4][4];
#pragma unroll
    for (int i = 0; i < 2; ++i)
#pragma unroll
      for (int r = 0; r < 4; ++r) {
        const int tloc = wm * 32 + i * 16 + quad * 4 + r;
#pragma unroll
        for (int j = 0; j < 4; ++j) {
          const int d32 = (j & 1) * 16 + lrow;   // d mod 32
          float val = acc[i][j][r] * outscale;
          if (btype < 2) {
            float rotv =
                ((j < 2) ? -acc[i][j + 2][r] : acc[i][j - 2][r]) * outscale;
            val = val * cs[tloc * 36 + d32] + rotv * sn[tloc * 36 + d32];
          }
          fv[i][r][j] = val;
        }
      }
    // direct (t,d) fp16 hi/lo stores for q and k (den-critical: keep split)
    if (btype < 2) {
      _Float16* dh = (btype == 0 ? qh_ : kh_) + hb;
      _Float16* dl = (btype == 0 ? ql_ : kl_) + hb;
#pragma unroll
      for (int i = 0; i < 2; ++i)
#pragma unroll
        for (int r = 0; r < 4; ++r) {
          const size_t trow =
              (size_t)(bm + wm * 32 + i * 16 + quad * 4 + r) * D_DIM;
#pragma unroll
          for (int j = 0; j < 4; ++j) {
            const int d = j * 16 + lrow;
            float f = fv[i][r][j];
            _Float16 hh = (_Float16)f;
            dh[trow + d] = hh;
            dl[trow + d] = (_Float16)(f - (float)hh);
          }
        }
    }
    // transposed (d,t) stores: k hi+lo (ksum is den-critical), v hi only.
    if (btype >= 1) {
      _Float16* th = (btype == 1 ? kTh_ : vTh_) + hb;
      _Float16* tl = kTl_ + hb;      // used only when btype == 1
      float* myb = bounce + wn * 4096;
#pragma unroll
      for (int i = 0; i < 2; ++i)
#pragma unroll
        for (int r = 0; r < 4; ++r) {
          const int tloc = wm * 32 + i * 16 + quad * 4 + r;
#pragma unroll
          for (int j = 0; j < 4; ++j) {
            const int d = j * 16 + lrow;
            myb[tloc * 64 + (d ^ tloc)] = fv[i][r][j];
          }
        }
      __syncthreads();
      const int lt = wm * 64 + lane;   // 0..127 over the 2 same-wn waves
      const int e = lt >> 1;           // output row (dim)
      const int tg0 = (lt & 1) * 32;   // 32-t half
#pragma unroll
      for (int s8 = 0; s8 < 4; ++s8) {
        h8 hv, lv;
#pragma unroll
        for (int s = 0; s < 8; ++s) {
          const int t = tg0 + s8 * 8 + s;
          float f = myb[t * 64 + (e ^ t)];
          _Float16 hh = (_Float16)f;
          hv[s] = hh;
          lv[s] = (_Float16)(f - (float)hh);
        }
        *(h8*)&th[(size_t)e * T_LEN + bm + tg0 + s8 * 8] = hv;
        if (btype == 1)
          *(h8*)&tl[(size_t)e * T_LEN + bm + tg0 + s8 * 8] = lv;
      }
    }
  }
}

// ---------------------------------------------------------------------------
// Per-(head,chunk) KV^T via MFMA: kvT[e][d] = sum_t v[t][e]*k[t][d].
// kv product is num-path -> hi*hi only (8 MFMAs). ksum (den-path) uses
// kTh+kTl exactly; vsum (num-path) hi only. Global-direct frags, no LDS.
// ---------------------------------------------------------------------------
__global__ __launch_bounds__(256) void chunk_kvT(
    const _Float16* __restrict__ kTh, const _Float16* __restrict__ kTl,
    const _Float16* __restrict__ vTh, float* __restrict__ kvchunk,
    float* __restrict__ kschunk, float* __restrict__ vschunk) {
  const int blk = blockIdx.x;  // h*NC + c
  const int h = blk / NC, c = blk % NC;
  const int tid = threadIdx.x;
  const int wave = tid >> 6, lane = tid & 63;
  const int quad = lane >> 4, lrow = lane & 15;
  const size_t hb = (size_t)h * D_DIM * T_LEN;
  const int tb = c * L_CHK;
  // A-frags: vT rows e = wave*16+lrow, t-range = ks*32 + quad*8
  h8 avh[2];
  {
    const _Float16* pa = vTh + hb + (size_t)(wave * 16 + lrow) * T_LEN + tb +
                         quad * 8;
    avh[0] = *(const h8*)pa;
    avh[1] = *(const h8*)(pa + 32);
  }
  f32x4 accv[4];
#pragma unroll
  for (int dt = 0; dt < 4; ++dt) accv[dt] = (f32x4){0.f, 0.f, 0.f, 0.f};
#pragma unroll
  for (int dt = 0; dt < 4; ++dt) {
    const _Float16* pb = kTh + hb + (size_t)(dt * 16 + lrow) * T_LEN + tb +
                         quad * 8;
#pragma unroll
    for (int ks = 0; ks < 2; ++ks) {
      h8 bh = *(const h8*)(pb + ks * 32);
      accv[dt] = __builtin_amdgcn_mfma_f32_16x16x32_f16(avh[ks], bh, accv[dt],
                                                        0, 0, 0);
    }
  }
  // store kvT: row e = wave*16 + quad*4 + reg, col d = dt*16 + lrow
  float* ob = kvchunk + (size_t)blk * (D_DIM * D_DIM);
#pragma unroll
  for (int dt = 0; dt < 4; ++dt)
#pragma unroll
    for (int r = 0; r < 4; ++r)
      ob[(wave * 16 + quad * 4 + r) * D_DIM + dt * 16 + lrow] = accv[dt][r];
  // ksum (exact hi+lo, den-path) / vsum (hi, num-path)
  if (tid < 64) {
    const _Float16* p = kTh + hb + (size_t)tid * T_LEN + tb;
    const _Float16* pl = kTl + hb + (size_t)tid * T_LEN + tb;
    float s = 0.f;
#pragma unroll
    for (int i = 0; i < 8; ++i) {
      h8 a = *(const h8*)(p + i * 8), b = *(const h8*)(pl + i * 8);
#pragma unroll
      for (int m = 0; m < 8; ++m) s += (float)a[m] + (float)b[m];
    }
    kschunk[(size_t)blk * D_DIM + tid] = s;
  } else if (tid < 128) {
    const int e = tid - 64;
    const _Float16* p = vTh + hb + (size_t)e * T_LEN + tb;
    float s = 0.f;
#pragma unroll
    for (int i = 0; i < 8; ++i) {
      h8 a = *(const h8*)(p + i * 8);
#pragma unroll
      for (int m = 0; m < 8; ++m) s += (float)a[m];
    }
    vschunk[(size_t)blk * D_DIM + e] = s;
  }
}

// ---------------------------------------------------------------------------
// Fused exclusive prefix scans over chunks. kv state accumulates fp32 but is
// EMITTED as fp16 (num-path tolerance). Vectors stay fp32 (den-path).
// ---------------------------------------------------------------------------
__global__ __launch_bounds__(256) void scan_fused(
    const float* __restrict__ kvchunk, _Float16* __restrict__ kvph,
    const float* __restrict__ kschunk, const float* __restrict__ vschunk,
    float* __restrict__ kspref, float* __restrict__ vspref) {
  int b = blockIdx.x;
  int tid = threadIdx.x;
  if (b < 256) {
    int gid = b * 256 + tid;  // h*4096 + de
    int h = gid >> 12;
    int de = gid & 4095;
    float vals[NC];
#pragma unroll
    for (int c = 0; c < NC; ++c)
      vals[c] = kvchunk[((size_t)(h * NC + c) << 12) + de];
    float run = 0.f;
#pragma unroll
    for (int c = 0; c < NC; ++c) {
      kvph[((size_t)(h * NC + c) << 12) + de] = (_Float16)run;
      run += vals[c];
    }
  } else {
    int gid = (b - 256) * 256 + tid;  // h*64 + d (total 1024)
    int h = gid >> 6, d = gid & 63;
    float kv_[NC], vv_[NC];
#pragma unroll
    for (int c = 0; c < NC; ++c) {
      size_t idx = (size_t)(h * NC + c) * 64 + d;
      kv_[c] = kschunk[idx];
      vv_[c] = vschunk[idx];
    }
    float rk = 0.f, rv = 0.f;
#pragma unroll
    for (int c = 0; c < NC; ++c) {
      size_t idx = (size_t)(h * NC + c) * 64 + d;
      kspref[idx] = rk;
      vspref[idx] = rv;
      rk += kv_[c];
      rv += vv_[c];
    }
  }
}

// ---------------------------------------------------------------------------
// MFMA attention output. One block per (h,c), 4 waves; wave w owns rows
// [w*16, w*16+16) x all 64 e-cols.
//   S = Q K^T split3 (den-critical) -> mask/+1 -> fp16 hi/lo wave-private
//   swizzled LDS; rowsum via ones-MFMA on Sh+Sl (den); S.V = (Sh+Sl).Vh;
//   q.KVpref = qh.KVh (num, fp16 direct); q.kspref split3 (den).
// No __syncthreads (all LDS wave-private).
// ---------------------------------------------------------------------------
__global__ __launch_bounds__(256) void attn_mfma(
    const _Float16* __restrict__ qh, const _Float16* __restrict__ ql,
    const _Float16* __restrict__ kh, const _Float16* __restrict__ kl,
    const _Float16* __restrict__ vTh, const _Float16* __restrict__ kvph,
    const float* __restrict__ kspref, const float* __restrict__ vspref,
    _Float16* __restrict__ yh) {
  __shared__ __align__(16) _Float16 sS[2][4][16 * 64];  // [plane][wave][r*64+j]
  const int blk = blockIdx.x;  // h*NC + c
  const int h = blk / NC, c = blk % NC;
  const int tid = threadIdx.x;
  const int wave = tid >> 6, lane = tid & 63;
  const int quad = lane >> 4, lrow = lane & 15;
  const size_t hb = (size_t)h * T_LEN * D_DIM;   // (t,d) arrays
  const size_t hbT = (size_t)h * D_DIM * T_LEN;  // (e,t) arrays
  const int t0 = c * L_CHK;
  const f32x4 z4 = {0.f, 0.f, 0.f, 0.f};
  // Q A-frags: rows t0 + wave*16 + lrow, d-range ks*32 + quad*8
  h8 aqh[2], aql[2];
  {
    const _Float16* pq =
        qh + hb + (size_t)(t0 + wave * 16 + lrow) * D_DIM + quad * 8;
    const _Float16* pql =
        ql + hb + (size_t)(t0 + wave * 16 + lrow) * D_DIM + quad * 8;
    aqh[0] = *(const h8*)pq;
    aqh[1] = *(const h8*)(pq + 32);
    aql[0] = *(const h8*)pql;
    aql[1] = *(const h8*)(pql + 32);
  }
  // Phase 1: S = Q K^T (within-chunk), 4 col-tiles, split3 (den-critical)
  f32x4 sacc[4];
#pragma unroll
  for (int jt = 0; jt < 4; ++jt) sacc[jt] = z4;
#pragma unroll
  for (int jt = 0; jt < 4; ++jt) {
    const _Float16* pk =
        kh + hb + (size_t)(t0 + jt * 16 + lrow) * D_DIM + quad * 8;
    const _Float16* pkl =
        kl + hb + (size_t)(t0 + jt * 16 + lrow) * D_DIM + quad * 8;
#pragma unroll
    for (int ks = 0; ks < 2; ++ks) {
      h8 bh = *(const h8*)(pk + ks * 32);
      h8 bl = *(const h8*)(pkl + ks * 32);
      sacc[jt] = __builtin_amdgcn_mfma_f32_16x16x32_f16(aqh[ks], bh, sacc[jt],
                                                        0, 0, 0);
      sacc[jt] = __builtin_amdgcn_mfma_f32_16x16x32_f16(aqh[ks], bl, sacc[jt],
                                                        0, 0, 0);
      sacc[jt] = __builtin_amdgcn_mfma_f32_16x16x32_f16(aql[ks], bh, sacc[jt],
                                                        0, 0, 0);
    }
  }
  // mask, +1, fp16 split, stage (swizzled: 8-half blocks XOR'd by row&7)
  _Float16* shp = &sS[0][wave][0];
  _Float16* slp = &sS[1][wave][0];
#pragma unroll
  for (int jt = 0; jt < 4; ++jt)
#pragma unroll
    for (int r = 0; r < 4; ++r) {
      const int row = quad * 4 + r;          // band-local row
      const int j = jt * 16 + lrow;          // chunk-local col
      const int rglob = wave * 16 + row;
      float s = (j <= rglob) ? (sacc[jt][r] + 1.f) : 0.f;
      _Float16 hh = (_Float16)s;
      const int adr = row * 64 + ((((j >> 3) ^ (row & 7)) << 3) | (j & 7));
      shp[adr] = hh;
      slp[adr] = (_Float16)(s - (float)hh);
    }
  // S A-frags (own band, same-wave LDS dependency)
  h8 ash[2], asl[2];
#pragma unroll
  for (int ks = 0; ks < 2; ++ks) {
    const int adr = lrow * 64 + (((ks * 4 + quad) ^ (lrow & 7)) << 3);
    ash[ks] = *(const h8*)&shp[adr];
    asl[ks] = *(const h8*)&slp[adr];
  }
  // rowsum(S) via ones-fragment (exact: Sh+Sl; den-critical)
  h8 ones;
#pragma unroll
  for (int m = 0; m < 8; ++m) ones[m] = (_Float16)1.0f;
  f32x4 rs = z4;
#pragma unroll
  for (int ks = 0; ks < 2; ++ks) {
    rs = __builtin_amdgcn_mfma_f32_16x16x32_f16(ash[ks], ones, rs, 0, 0, 0);
    rs = __builtin_amdgcn_mfma_f32_16x16x32_f16(asl[ks], ones, rs, 0, 0, 0);
  }
  // out accumulation: S.V = (Sh+Sl).Vh (num-path)
  f32x4 oacc[4];
#pragma unroll
  for (int et = 0; et < 4; ++et) oacc[et] = z4;
#pragma unroll
  for (int et = 0; et < 4; ++et) {
    const _Float16* pv =
        vTh + hbT + (size_t)(et * 16 + lrow) * T_LEN + t0 + quad * 8;
#pragma unroll
    for (int ks = 0; ks < 2; ++ks) {
      h8 bh = *(const h8*)(pv + ks * 32);
      oacc[et] = __builtin_amdgcn_mfma_f32_16x16x32_f16(ash[ks], bh, oacc[et],
                                                        0, 0, 0);
      oacc[et] = __builtin_amdgcn_mfma_f32_16x16x32_f16(asl[ks], bh, oacc[et],
                                                        0, 0, 0);
    }
  }
  // q . KVpref (num-path, fp16 direct)
  const _Float16* kvp = kvph + ((size_t)blk << 12);
#pragma unroll
  for (int et = 0; et < 4; ++et) {
#pragma unroll
    for (int ks = 0; ks < 2; ++ks) {
      h8 bh = *(const h8*)&kvp[(et * 16 + lrow) * D_DIM + ks * 32 + quad * 8];
      oacc[et] = __builtin_amdgcn_mfma_f32_16x16x32_f16(aqh[ks], bh, oacc[et],
                                                        0, 0, 0);
    }
  }
  // den extra: q . kspref split3 via broadcast fragment (den-critical)
  const float* ksp = kspref + (size_t)blk * D_DIM;
  f32x4 kacc = z4;
#pragma unroll
  for (int ks = 0; ks < 2; ++ks) {
    const float* pb = ksp + ks * 32 + quad * 8;
    float4 b0 = *(const float4*)pb;
    float4 b1 = *(const float4*)(pb + 4);
    h8 bh, bl;
    split8(b0, b1, bh, bl);
    kacc = __builtin_amdgcn_mfma_f32_16x16x32_f16(aqh[ks], bh, kacc, 0, 0, 0);
    kacc = __builtin_amdgcn_mfma_f32_16x16x32_f16(aqh[ks], bl, kacc, 0, 0, 0);
    kacc = __builtin_amdgcn_mfma_f32_16x16x32_f16(aql[ks], bh, kacc, 0, 0, 0);
  }
  // epilogue: den = c*64 + rowsum + q.ksp ; out = (vsp + oacc) / den
  const float* vsp = vspref + (size_t)blk * D_DIM;
#pragma unroll
  for (int r = 0; r < 4; ++r) {
    const int row = wave * 16 + quad * 4 + r;  // chunk-local t
    const float den = (float)(c * L_CHK) + rs[r] + kacc[r];
    const float inv = 1.f / den;
    const size_t ybase = (size_t)(t0 + row) * (H_NUM * D_DIM) + h * D_DIM;
#pragma unroll
    for (int et = 0; et < 4; ++et) {
      const int e = et * 16 + lrow;
      const float num = oacc[et][r] + vsp[e];
      yh[ybase + e] = (_Float16)(num * inv);
    }
  }
}

// ---------------------------------------------------------------------------
extern "C" void kernel_launch(void* const* d_in, const int* in_sizes, int n_in,
                              void* d_out, int out_size, void* d_ws,
                              size_t ws_size, hipStream_t stream) {
  const float* x = (const float*)d_in[0];       // (1,2048,1024)
  const float* w_attn = (const float*)d_in[1];  // (3072,1024)
  const float* w_proj = (const float*)d_in[2];  // (1024,1024)
  const float* cosb = (const float*)d_in[3];    // (2048,64)
  const float* sinb = (const float*)d_in[4];    // (2048,64)
  float* out = (float*)d_out;                   // (2048,1024)

  char* ws = (char*)d_ws;
  const size_t MB = 1048576;
  // 0..8MB: kvchunk fp32; 8..12MB: kvph fp16 prefix
  float* kvchunk = (float*)ws;
  _Float16* kvph = (_Float16*)(ws + 8 * MB);
  // 16..44MB: fp16 q,k hi/lo (t,d); kT hi/lo, vT hi (d/e, t)
  _Float16* qh = (_Float16*)(ws + 16 * MB);
  _Float16* ql = (_Float16*)(ws + 20 * MB);
  _Float16* kh = (_Float16*)(ws + 24 * MB);
  _Float16* kl = (_Float16*)(ws + 28 * MB);
  _Float16* kTh = (_Float16*)(ws + 32 * MB);
  _Float16* kTl = (_Float16*)(ws + 36 * MB);
  _Float16* vTh = (_Float16*)(ws + 40 * MB);
  // 48..56MB: xh/xl (live split->QKV GEMM); then yh.
  _Float16* xh = (_Float16*)(ws + 48 * MB);
  _Float16* xl = (_Float16*)(ws + 52 * MB);
  _Float16* yh = (_Float16*)(ws + 48 * MB);
  // 56..68MB: wah/wal (live split->QKV GEMM); then scan vectors.
  _Float16* wah = (_Float16*)(ws + 56 * MB);
  _Float16* wal = (_Float16*)(ws + 62 * MB);
  float* kschunk = (float*)(ws + 56 * MB);
  float* vschunk = (float*)(ws + 56 * MB + 131072);
  float* kspref = (float*)(ws + 56 * MB + 262144);
  float* vspref = (float*)(ws + 56 * MB + 393216);
  // 68..70MB: wph (live whole call).
  _Float16* wph = (_Float16*)(ws + 68 * MB);

  // 0) fused splits (scale 64, undone in epilogues); w_proj hi-only
  split3_f16<<<3072, 256, 0, stream>>>(x, xh, xl, w_attn, wah, wal, w_proj,
                                       wph);

  // 1) qkv GEMM (type-uniform blocks; v-blocks hi*hi) + fused RoPE
  {
    dim3 grid(QKV_N / 128, T_LEN / 64);   // 24 x 32 = 768 blocks
    gemm_nt_f16<128, true, true><<<grid, 256, 0, stream>>>(
        xh, xl, wah, wal, nullptr, cosb, sinb, qh, ql, kh, kl, kTh, kTl, vTh,
        T_LEN, QKV_N, C_DIM, 1.f / 4096.f);
  }
  // 2) per-chunk KV^T (hi*hi) + exact ksum / hi vsum
  chunk_kvT<<<H_NUM * NC, 256, 0, stream>>>(kTh, kTl, vTh, kvchunk, kschunk,
                                            vschunk);
  // 3) fused prefix scans (kv -> fp16; vectors fp32)
  scan_fused<<<260, 256, 0, stream>>>(kvchunk, kvph, kschunk, vschunk,
                                      kspref, vspref);
  // 4) MFMA attention output -> yh (T, H*D) fp16
  attn_mfma<<<H_NUM * NC, 256, 0, stream>>>(qh, ql, kh, kl, vTh, kvph,
                                            kspref, vspref, yh);
  // 5) out = y @ w_proj^T (plain fp16, BN=128, 6 blocks/CU): 2^-6
  {
    dim3 grid(C_DIM / 128, T_LEN / 64);   // 8 x 32 = 256 blocks
    gemm_nt_f16<128, false, false><<<grid, 256, 0, stream>>>(
        yh, nullptr, wph, nullptr, out, nullptr, nullptr, nullptr, nullptr,
        nullptr, nullptr, nullptr, nullptr, nullptr, T_LEN, C_DIM, C_DIM,
        1.f / 64.f);
  }
}